// Round 7
// baseline (324.345 us; speedup 1.0000x reference)
//
#include <hip/hip_runtime.h>
#include <cstdint>
#include <cstddef>

// Qwen3AttentionModified: B=1 S=2048 D=2048 H=16 KVH=8 HD=128
// cast hs->bf16; transpose+cast weights; QKV GEMM (+XCD swizzle); RoPE -> Q/K bf16;
// V -> bf16 [kvh][d][s]; attention v7: ONE WAVE PER BLOCK (h, 16 q-rows), no LDS,
// no barriers, swapped-QK^T zero-shuffle pack (r5/r6-verified math), K ping-pong
// prefetch, V issued early, LPT order + kvh->XCD binding; O GEMM (BM=64) -> fp32.

namespace {
constexpr int kS = 2048;
constexpr int kD = 2048;
constexpr int kH = 16;
constexpr int kKVH = 8;
constexpr int kHD = 128;
constexpr float kScale = 0.08838834764831845f;  // 128^-0.5
constexpr size_t MB = 1u << 20;
}  // namespace

using f32x4 = __attribute__((ext_vector_type(4))) float;
using bfrag = __attribute__((ext_vector_type(8))) short;   // 8 x bf16 (4 VGPR)
using float4v = __attribute__((ext_vector_type(4))) float;
using short4v = __attribute__((ext_vector_type(4))) short;

__device__ __forceinline__ unsigned short f2b(float f) {
  union { float f; unsigned u; } x; x.f = f;
  unsigned r = x.u + 0x7FFFu + ((x.u >> 16) & 1u);  // RNE
  return (unsigned short)(r >> 16);
}

__device__ __forceinline__ void gload_lds16(const void* g, void* l) {
  __builtin_amdgcn_global_load_lds(
      (const __attribute__((address_space(1))) unsigned*)g,
      (__attribute__((address_space(3))) unsigned*)l, 16, 0, 0);
}

// ---------------- cast fp32 -> bf16 ----------------
__global__ __launch_bounds__(256) void qwen_cast_bf16(const float* __restrict__ in,
                                                      unsigned short* __restrict__ out,
                                                      int n4) {
  int i = blockIdx.x * 256 + threadIdx.x;
  if (i >= n4) return;
  float4v v = *(const float4v*)(in + (size_t)i * 4);
  short4v o;
  o[0] = (short)f2b(v[0]); o[1] = (short)f2b(v[1]);
  o[2] = (short)f2b(v[2]); o[3] = (short)f2b(v[3]);
  *(short4v*)(out + (size_t)i * 4) = o;
}

// ------------- transpose + cast: fp32 [R][C] -> bf16 [C][ldo] -------------
__global__ __launch_bounds__(256) void qwen_tw(const float* __restrict__ in, int R, int C,
                                               unsigned short* __restrict__ out, int ldo) {
  __shared__ float t[64][65];
  int c0 = blockIdx.x * 64, r0 = blockIdx.y * 64;
  int tr = threadIdx.x >> 6, tc = threadIdx.x & 63;
#pragma unroll
  for (int p = 0; p < 16; ++p) {
    int i = p * 4 + tr;
    t[i][tc] = in[(size_t)(r0 + i) * C + c0 + tc];
  }
  __syncthreads();
#pragma unroll
  for (int p = 0; p < 16; ++p) {
    int i = p * 4 + tr;
    out[(size_t)(c0 + i) * ldo + r0 + tc] = f2b(t[tc][i]);
  }
}

// ------------- GEMM (m97 structure + XCD swizzle): C fp32 = A[M][K] @ Bt[N][K] -------------
template <int BM>
__global__ __launch_bounds__(256) void qwen_gemm_bt(const unsigned short* __restrict__ A,
                                                    const unsigned short* __restrict__ Bt,
                                                    float* __restrict__ C,
                                                    int M, int N, int K) {
  __shared__ unsigned short As[BM * 32];
  __shared__ unsigned short Bs[128 * 32];
  constexpr int MR = BM / 32;
  const int nwg = gridDim.x * gridDim.y;
  int lin = blockIdx.y * gridDim.x + blockIdx.x;
  if ((nwg & 7) == 0) { int qq = nwg >> 3; lin = (lin & 7) * qq + (lin >> 3); }
  const int bxx = lin % gridDim.x, byy = lin / gridDim.x;
  const int tid = threadIdx.x, lane = tid & 63, w = tid >> 6;
  const int wr = w >> 1, wc = w & 1;
  const int row0 = bxx * BM, col0 = byy * 128;
  f32x4 acc[MR][4] = {};
  const int koff = (lane >> 4) << 3;
  const int rA = wr * (BM / 2) + (lane & 15);
  const int rB = wc * 64 + (lane & 15);
  for (int kt = 0; kt < K; kt += 32) {
#pragma unroll
    for (int c = 0; c < BM / 64; ++c) {
      int off = (c * 256 + tid) * 16;
      int e = off >> 1;
      int r = e >> 5, cc = e & 31;
      gload_lds16(A + (size_t)(row0 + r) * K + kt + cc, (char*)As + off);
    }
#pragma unroll
    for (int c = 0; c < 2; ++c) {
      int off = (c * 256 + tid) * 16;
      int e = off >> 1;
      int r = e >> 5, cc = e & 31;
      gload_lds16(Bt + (size_t)(col0 + r) * K + kt + cc, (char*)Bs + off);
    }
    __syncthreads();
    bfrag aF[MR], bF[4];
#pragma unroll
    for (int m = 0; m < MR; ++m) aF[m] = *(const bfrag*)(As + (rA + m * 16) * 32 + koff);
#pragma unroll
    for (int n = 0; n < 4; ++n) bF[n] = *(const bfrag*)(Bs + (rB + n * 16) * 32 + koff);
#pragma unroll
    for (int m = 0; m < MR; ++m)
#pragma unroll
      for (int n = 0; n < 4; ++n)
        acc[m][n] = __builtin_amdgcn_mfma_f32_16x16x32_bf16(aF[m], bF[n], acc[m][n], 0, 0, 0);
    __syncthreads();
  }
  const int cr = (lane >> 4) << 2;
  const int cc2 = lane & 15;
#pragma unroll
  for (int m = 0; m < MR; ++m)
#pragma unroll
    for (int n = 0; n < 4; ++n) {
      int r = row0 + wr * (BM / 2) + m * 16 + cr;
      int c = col0 + wc * 64 + n * 16 + cc2;
#pragma unroll
      for (int j = 0; j < 4; ++j) C[(size_t)(r + j) * N + c] = acc[m][n][j];
    }
}

// ------------- RoPE epilogue: Q,K -> bf16 [h][s][d] -------------
__global__ __launch_bounds__(256) void qwen_rope_qk(const float* __restrict__ Cqkv,
                                                    const float* __restrict__ cosb,
                                                    const float* __restrict__ sinb,
                                                    const float* __restrict__ qnw,
                                                    const float* __restrict__ knw,
                                                    const float* __restrict__ qden,
                                                    const float* __restrict__ kden,
                                                    unsigned short* __restrict__ Qb,
                                                    unsigned short* __restrict__ Kb) {
  int s = blockIdx.x;
  int t = threadIdx.x;
  const float* row = Cqkv + (size_t)s * 4096;
  const float* cs = cosb + (size_t)s * kHD;
  const float* sn = sinb + (size_t)s * kHD;
#pragma unroll
  for (int rep = 0; rep < 8; ++rep) {
    int idx = rep * 256 + t;
    int h = idx >> 7, d = idx & 127;
    float dn = qden[s * kH + h];
    float v = row[idx] * dn * qnw[d];
    float pv = row[(h << 7) + (d ^ 64)] * dn * qnw[d ^ 64];
    float rot = (d < 64) ? -pv : pv;
    Qb[((size_t)h * kS + s) * kHD + d] = f2b(v * cs[d] + rot * sn[d]);
  }
#pragma unroll
  for (int rep = 0; rep < 4; ++rep) {
    int idx = rep * 256 + t;
    int h = idx >> 7, d = idx & 127;
    float dn = kden[s * kKVH + h];
    float v = row[2048 + idx] * dn * knw[d];
    float pv = row[2048 + (h << 7) + (d ^ 64)] * dn * knw[d ^ 64];
    float rot = (d < 64) ? -pv : pv;
    Kb[((size_t)h * kS + s) * kHD + d] = f2b(v * cs[d] + rot * sn[d]);
  }
}

// ------------- V -> bf16 [kvh][d][s] -------------
__global__ __launch_bounds__(256) void qwen_vtr(const float* __restrict__ Cqkv,
                                                unsigned short* __restrict__ Vt) {
  __shared__ float t[64][65];
  int kvh = blockIdx.x, st = blockIdx.y, dt = blockIdx.z;
  int s0 = st * 64, d0 = dt * 64;
  int tr = threadIdx.x >> 6, tc = threadIdx.x & 63;
#pragma unroll
  for (int p = 0; p < 16; ++p) {
    int i = p * 4 + tr;
    t[i][tc] = Cqkv[(size_t)(s0 + i) * 4096 + 3072 + (kvh << 7) + d0 + tc];
  }
  __syncthreads();
#pragma unroll
  for (int p = 0; p < 16; ++p) {
    int i = p * 4 + tr;
    Vt[(size_t)((kvh << 7) + d0 + i) * kS + s0 + tc] = f2b(t[tc][i]);
  }
}

// ------------- attention v7: one wave per block, no LDS, no barriers -------------
// 2048 blocks x 64 threads. kvh = bid&7 (XCD L2 binding); j = bid>>3 in [0,256):
// qt16 = 127 - (j>>1) (LPT: longest first), h = kvh*2 + (j&1). Wave owns q-rows
// [q0, q0+16), loops over chunks of 32 keys (nch = (q0+47)>>5).
// Swapped QK^T: S^T = mfma(K,Q) col=q=l15, row=key=g*4+r. ew+pack in regs gives
// the PV B-frag (k-slot g*8+j <-> key k0+(j>=4)*16+g*4+(j&3)); V^T b64-pair loads
// form the matching A-frag. outa = out^T[d][q] accumulates across all chunks.
#define CHUNK7(KC, KN)                                                                  \
  do {                                                                                  \
    const int k0 = c * 32;                                                              \
    union { bfrag f; short4v h4[2]; } va[8];                                            \
    _Pragma("unroll") for (int dt = 0; dt < 8; ++dt) {                                  \
      const unsigned short* vp = Vg + (size_t)(dt * 16 + l15) * kS + k0 + g * 4;        \
      va[dt].h4[0] = *(const short4v*)vp;                                               \
      va[dt].h4[1] = *(const short4v*)(vp + 16);                                        \
    }                                                                                   \
    f32x4 sc[2] = {{0, 0, 0, 0}, {0, 0, 0, 0}};                                         \
    _Pragma("unroll") for (int n2 = 0; n2 < 2; ++n2)                                    \
      _Pragma("unroll") for (int dc = 0; dc < 4; ++dc)                                  \
        sc[n2] = __builtin_amdgcn_mfma_f32_16x16x32_bf16(KC[n2][dc], qF[dc],            \
                                                         sc[n2], 0, 0, 0);              \
    if (c + 1 < nch) {                                                                  \
      const unsigned short* kp = Kg + (size_t)((c + 1) * 32 + l15) * kHD + g * 8;       \
      _Pragma("unroll") for (int n2 = 0; n2 < 2; ++n2)                                  \
        _Pragma("unroll") for (int dc = 0; dc < 4; ++dc)                                \
          KN[n2][dc] = *(const bfrag*)(kp + (size_t)n2 * 16 * kHD + dc * 32);           \
    }                                                                                   \
    const bool full = (k0 + 31 <= q0);                                                  \
    union { bfrag f; unsigned u[4]; } pb;                                               \
    _Pragma("unroll") for (int n2 = 0; n2 < 2; ++n2) {                                  \
      unsigned short b[4];                                                              \
      _Pragma("unroll") for (int rr = 0; rr < 4; ++rr) {                                \
        float t = sc[n2][rr] * kScale;                                                  \
        if (full) {                                                                     \
          t += 7.0f;                                                                    \
        } else {                                                                        \
          int key = k0 + n2 * 16 + g * 4 + rr;                                          \
          t += (key <= q0 + l15) ? 7.0f : 0.0f;                                         \
        }                                                                               \
        float y = t * inv;                                                              \
        float y2 = y * y, y4 = y2 * y2;                                                 \
        b[rr] = f2b(y4 * y4);                                                           \
      }                                                                                 \
      pb.u[n2 * 2 + 0] = (unsigned)b[0] | ((unsigned)b[1] << 16);                       \
      pb.u[n2 * 2 + 1] = (unsigned)b[2] | ((unsigned)b[3] << 16);                       \
    }                                                                                   \
    _Pragma("unroll") for (int dt = 0; dt < 8; ++dt)                                    \
      outa[dt] = __builtin_amdgcn_mfma_f32_16x16x32_bf16(va[dt].f, pb.f,                \
                                                         outa[dt], 0, 0, 0);            \
  } while (0)

__global__ __launch_bounds__(64, 3) void qwen_attn(const unsigned short* __restrict__ Qb,
                                                   const unsigned short* __restrict__ Kb,
                                                   const unsigned short* __restrict__ Vtb,
                                                   const float* __restrict__ rd,
                                                   unsigned short* __restrict__ AO) {
  const int bid = blockIdx.x;
  const int kvh = bid & 7;
  const int j = bid >> 3;              // 0..255
  const int qt16 = 127 - (j >> 1);     // LPT: longest first
  const int h = kvh * 2 + (j & 1);
  const int q0 = qt16 * 16;
  const int nch = (q0 + 47) >> 5;      // chunks of 32 keys covering 0..q0+15
  const int lane = threadIdx.x & 63;
  const int l15 = lane & 15, g = lane >> 4;

  const unsigned short* Kg = Kb + (size_t)kvh * kS * kHD;
  const unsigned short* Vg = Vtb + (size_t)kvh * kHD * kS;

  // Q frags (B-operand: col=q=l15, k=d)
  bfrag qF[4];
#pragma unroll
  for (int dc = 0; dc < 4; ++dc)
    qF[dc] = *(const bfrag*)(Qb + ((size_t)h * kS + q0 + l15) * kHD + dc * 32 + g * 8);
  const float inv = 1.0f / rd[(size_t)h * kS + q0 + l15];

  f32x4 outa[8] = {};  // out^T: col=q=l15, row=d=g*4+r per 16-d tile

  bfrag kA[2][4], kB[2][4];
  {
    const unsigned short* kp = Kg + (size_t)l15 * kHD + g * 8;
#pragma unroll
    for (int n2 = 0; n2 < 2; ++n2)
#pragma unroll
      for (int dc = 0; dc < 4; ++dc)
        kA[n2][dc] = *(const bfrag*)(kp + (size_t)n2 * 16 * kHD + dc * 32);
  }
  int c = 0;
  while (true) {
    CHUNK7(kA, kB);
    ++c; if (c == nch) break;
    CHUNK7(kB, kA);
    ++c; if (c == nch) break;
  }
  // AO bf16 [s][h*128+d]
#pragma unroll
  for (int dt = 0; dt < 8; ++dt) {
    short4v o;
    o[0] = (short)f2b(outa[dt][0]); o[1] = (short)f2b(outa[dt][1]);
    o[2] = (short)f2b(outa[dt][2]); o[3] = (short)f2b(outa[dt][3]);
    *(short4v*)(AO + (size_t)(q0 + l15) * kD + h * 128 + dt * 16 + g * 4) = o;
  }
}

extern "C" void kernel_launch(void* const* d_in, const int* in_sizes, int n_in,
                              void* d_out, int out_size, void* d_ws, size_t ws_size,
                              hipStream_t stream) {
  (void)in_sizes; (void)n_in; (void)out_size; (void)ws_size;
  const float* hidden = (const float*)d_in[0];
  const float* cosb   = (const float*)d_in[1];
  const float* sinb   = (const float*)d_in[2];
  const float* qw     = (const float*)d_in[3];
  const float* kw     = (const float*)d_in[4];
  const float* vw     = (const float*)d_in[5];
  const float* ow     = (const float*)d_in[6];
  const float* qnw    = (const float*)d_in[7];
  const float* knw    = (const float*)d_in[8];
  const float* qden   = (const float*)d_in[9];
  const float* kden   = (const float*)d_in[10];
  const float* rd     = (const float*)d_in[11];
  float* out = (float*)d_out;

  char* ws = (char*)d_ws;
  unsigned short* hsb  = (unsigned short*)(ws + 0 * MB);   //  8 MB
  unsigned short* Wt   = (unsigned short*)(ws + 8 * MB);   // 16 MB
  float*          Cqkv = (float*)(ws + 24 * MB);           // 32 MB
  unsigned short* Qb   = (unsigned short*)(ws + 56 * MB);  //  8 MB
  unsigned short* Kb   = (unsigned short*)(ws + 64 * MB);  //  4 MB
  unsigned short* Vtb  = (unsigned short*)(ws + 68 * MB);  //  4 MB
  unsigned short* AO   = (unsigned short*)(ws + 72 * MB);  //  8 MB
  unsigned short* Ot   = (unsigned short*)(ws + 80 * MB);  //  8 MB

  qwen_cast_bf16<<<4096, 256, 0, stream>>>(hidden, hsb, 2048 * 2048 / 4);
  qwen_tw<<<dim3(32, 32), 256, 0, stream>>>(qw, 2048, 2048, Wt, 2048);
  qwen_tw<<<dim3(16, 32), 256, 0, stream>>>(kw, 2048, 1024, Wt + (size_t)2048 * 2048, 2048);
  qwen_tw<<<dim3(16, 32), 256, 0, stream>>>(vw, 2048, 1024, Wt + (size_t)3072 * 2048, 2048);
  qwen_tw<<<dim3(32, 32), 256, 0, stream>>>(ow, 2048, 2048, Ot, 2048);
  qwen_gemm_bt<128><<<dim3(16, 32), 256, 0, stream>>>(hsb, Wt, Cqkv, 2048, 4096, 2048);
  qwen_rope_qk<<<2048, 256, 0, stream>>>(Cqkv, cosb, sinb, qnw, knw, qden, kden, Qb, Kb);
  qwen_vtr<<<dim3(8, 32, 2), 256, 0, stream>>>(Cqkv, Vtb);
  qwen_attn<<<2048, 64, 0, stream>>>(Qb, Kb, Vtb, rd, AO);
  qwen_gemm_bt<64><<<dim3(32, 16), 256, 0, stream>>>(AO, Ot, out, 2048, 2048, 2048);
}

// Round 8
// 184.526 us; speedup vs baseline: 1.7577x; 1.7577x over previous
//
#include <hip/hip_runtime.h>
#include <cstdint>
#include <cstddef>

// Qwen3AttentionModified: B=1 S=2048 D=2048 H=16 KVH=8 HD=128
// cast hs->bf16; transpose+cast weights; QKV GEMM (+XCD swizzle); RoPE -> Q bf16 +
// K pre-swizzled 16KB tiles; V -> pre-swizzled V^T tiles; attention v8: 4-wave block
// (h, 64 q-rows), global_load_lds double-buffered K/V, counted vmcnt(8) + raw
// barriers (T3/T4), swapped-QK^T zero-shuffle P->PV in registers (r5/r7-verified);
// O GEMM (BM=64) -> fp32 d_out.

namespace {
constexpr int kS = 2048;
constexpr int kD = 2048;
constexpr int kH = 16;
constexpr int kKVH = 8;
constexpr int kHD = 128;
constexpr float kScale = 0.08838834764831845f;  // 128^-0.5
constexpr size_t MB = 1u << 20;
}  // namespace

using f32x4 = __attribute__((ext_vector_type(4))) float;
using bfrag = __attribute__((ext_vector_type(8))) short;   // 8 x bf16 (4 VGPR)
using float4v = __attribute__((ext_vector_type(4))) float;
using short4v = __attribute__((ext_vector_type(4))) short;

__device__ __forceinline__ unsigned short f2b(float f) {
  union { float f; unsigned u; } x; x.f = f;
  unsigned r = x.u + 0x7FFFu + ((x.u >> 16) & 1u);  // RNE
  return (unsigned short)(r >> 16);
}

__device__ __forceinline__ void gload_lds16(const void* g, void* l) {
  __builtin_amdgcn_global_load_lds(
      (const __attribute__((address_space(1))) unsigned*)g,
      (__attribute__((address_space(3))) unsigned*)l, 16, 0, 0);
}

// ---------------- cast fp32 -> bf16 ----------------
__global__ __launch_bounds__(256) void qwen_cast_bf16(const float* __restrict__ in,
                                                      unsigned short* __restrict__ out,
                                                      int n4) {
  int i = blockIdx.x * 256 + threadIdx.x;
  if (i >= n4) return;
  float4v v = *(const float4v*)(in + (size_t)i * 4);
  short4v o;
  o[0] = (short)f2b(v[0]); o[1] = (short)f2b(v[1]);
  o[2] = (short)f2b(v[2]); o[3] = (short)f2b(v[3]);
  *(short4v*)(out + (size_t)i * 4) = o;
}

// ------------- transpose + cast: fp32 [R][C] -> bf16 [C][ldo] -------------
__global__ __launch_bounds__(256) void qwen_tw(const float* __restrict__ in, int R, int C,
                                               unsigned short* __restrict__ out, int ldo) {
  __shared__ float t[64][65];
  int c0 = blockIdx.x * 64, r0 = blockIdx.y * 64;
  int tr = threadIdx.x >> 6, tc = threadIdx.x & 63;
#pragma unroll
  for (int p = 0; p < 16; ++p) {
    int i = p * 4 + tr;
    t[i][tc] = in[(size_t)(r0 + i) * C + c0 + tc];
  }
  __syncthreads();
#pragma unroll
  for (int p = 0; p < 16; ++p) {
    int i = p * 4 + tr;
    out[(size_t)(c0 + i) * ldo + r0 + tc] = f2b(t[tc][i]);
  }
}

// ------------- GEMM (m97 structure + XCD swizzle): C fp32 = A[M][K] @ Bt[N][K] -------------
template <int BM>
__global__ __launch_bounds__(256) void qwen_gemm_bt(const unsigned short* __restrict__ A,
                                                    const unsigned short* __restrict__ Bt,
                                                    float* __restrict__ C,
                                                    int M, int N, int K) {
  __shared__ unsigned short As[BM * 32];
  __shared__ unsigned short Bs[128 * 32];
  constexpr int MR = BM / 32;
  const int nwg = gridDim.x * gridDim.y;
  int lin = blockIdx.y * gridDim.x + blockIdx.x;
  if ((nwg & 7) == 0) { int qq = nwg >> 3; lin = (lin & 7) * qq + (lin >> 3); }
  const int bxx = lin % gridDim.x, byy = lin / gridDim.x;
  const int tid = threadIdx.x, lane = tid & 63, w = tid >> 6;
  const int wr = w >> 1, wc = w & 1;
  const int row0 = bxx * BM, col0 = byy * 128;
  f32x4 acc[MR][4] = {};
  const int koff = (lane >> 4) << 3;
  const int rA = wr * (BM / 2) + (lane & 15);
  const int rB = wc * 64 + (lane & 15);
  for (int kt = 0; kt < K; kt += 32) {
#pragma unroll
    for (int c = 0; c < BM / 64; ++c) {
      int off = (c * 256 + tid) * 16;
      int e = off >> 1;
      int r = e >> 5, cc = e & 31;
      gload_lds16(A + (size_t)(row0 + r) * K + kt + cc, (char*)As + off);
    }
#pragma unroll
    for (int c = 0; c < 2; ++c) {
      int off = (c * 256 + tid) * 16;
      int e = off >> 1;
      int r = e >> 5, cc = e & 31;
      gload_lds16(Bt + (size_t)(col0 + r) * K + kt + cc, (char*)Bs + off);
    }
    __syncthreads();
    bfrag aF[MR], bF[4];
#pragma unroll
    for (int m = 0; m < MR; ++m) aF[m] = *(const bfrag*)(As + (rA + m * 16) * 32 + koff);
#pragma unroll
    for (int n = 0; n < 4; ++n) bF[n] = *(const bfrag*)(Bs + (rB + n * 16) * 32 + koff);
#pragma unroll
    for (int m = 0; m < MR; ++m)
#pragma unroll
      for (int n = 0; n < 4; ++n)
        acc[m][n] = __builtin_amdgcn_mfma_f32_16x16x32_bf16(aF[m], bF[n], acc[m][n], 0, 0, 0);
    __syncthreads();
  }
  const int cr = (lane >> 4) << 2;
  const int cc2 = lane & 15;
#pragma unroll
  for (int m = 0; m < MR; ++m)
#pragma unroll
    for (int n = 0; n < 4; ++n) {
      int r = row0 + wr * (BM / 2) + m * 16 + cr;
      int c = col0 + wc * 64 + n * 16 + cc2;
#pragma unroll
      for (int j = 0; j < 4; ++j) C[(size_t)(r + j) * N + c] = acc[m][n][j];
    }
}

// ------------- RoPE: Q -> bf16 [h][s][d]; K -> pre-swizzled 64-key tiles -------------
// Kswz tile (kvh, kt): 64 rows(key) x 128 us(d); elem idx = d ^ ((key&7)<<3)
__global__ __launch_bounds__(256) void qwen_rope_qk(const float* __restrict__ Cqkv,
                                                    const float* __restrict__ cosb,
                                                    const float* __restrict__ sinb,
                                                    const float* __restrict__ qnw,
                                                    const float* __restrict__ knw,
                                                    const float* __restrict__ qden,
                                                    const float* __restrict__ kden,
                                                    unsigned short* __restrict__ Qb,
                                                    unsigned short* __restrict__ Kswz) {
  int s = blockIdx.x;
  int t = threadIdx.x;
  const float* row = Cqkv + (size_t)s * 4096;
  const float* cs = cosb + (size_t)s * kHD;
  const float* sn = sinb + (size_t)s * kHD;
#pragma unroll
  for (int rep = 0; rep < 8; ++rep) {
    int idx = rep * 256 + t;
    int h = idx >> 7, d = idx & 127;
    float dn = qden[s * kH + h];
    float v = row[idx] * dn * qnw[d];
    float pv = row[(h << 7) + (d ^ 64)] * dn * qnw[d ^ 64];
    float rot = (d < 64) ? -pv : pv;
    Qb[((size_t)h * kS + s) * kHD + d] = f2b(v * cs[d] + rot * sn[d]);
  }
  const int kt = s >> 6, key = s & 63;
#pragma unroll
  for (int rep = 0; rep < 4; ++rep) {
    int idx = rep * 256 + t;
    int h = idx >> 7, d = idx & 127;  // h = kvh
    float dn = kden[s * kKVH + h];
    float v = row[2048 + idx] * dn * knw[d];
    float pv = row[2048 + (h << 7) + (d ^ 64)] * dn * knw[d ^ 64];
    float rot = (d < 64) ? -pv : pv;
    size_t rowi = ((size_t)(h * 32 + kt) * 64 + key) * 128;
    Kswz[rowi + (d ^ ((key & 7) << 3))] = f2b(v * cs[d] + rot * sn[d]);
  }
}

// ------------- V -> pre-swizzled V^T tiles: (kvh, kt): 128 rows(d) x 64 us(key) -------------
// elem idx = key ^ ((d&7)<<2)
__global__ __launch_bounds__(256) void qwen_vtr(const float* __restrict__ Cqkv,
                                                unsigned short* __restrict__ Vswz) {
  __shared__ float t[64][65];
  int kvh = blockIdx.x, st = blockIdx.y, dt = blockIdx.z;
  int s0 = st * 64, d0 = dt * 64;
  int tr = threadIdx.x >> 6, tc = threadIdx.x & 63;
#pragma unroll
  for (int p = 0; p < 16; ++p) {
    int i = p * 4 + tr;
    t[i][tc] = Cqkv[(size_t)(s0 + i) * 4096 + 3072 + (kvh << 7) + d0 + tc];
  }
  __syncthreads();
#pragma unroll
  for (int p = 0; p < 16; ++p) {
    int i = p * 4 + tr;
    int d = d0 + i;
    size_t rowi = ((size_t)(kvh * 32 + st) * 128 + d) * 64;
    Vswz[rowi + (tc ^ ((d & 7) << 2))] = f2b(t[tc][i]);
  }
}

// ------------- attention v8: counted-vmcnt pipeline, per-wave q ownership -------------
// 512 blocks x 256 thr. kvh=bid&7 (XCD-bound); h=kvh*2+((bid>>3)&1); qt=31-(bid>>4)
// (64-row q tile, heavy first). Wave w owns q rows qw0=qt*64+w*16 (+l15).
// Per 64-key chunk c: STAGE(c+1) -> vmcnt(8) -> barrier -> QK(16 mfma from swizzled
// LDS K) -> ew+pack in regs -> PV(16 mfma, V^T b64 pairs from LDS) -> barrier.
#define STAGE8(cc, bb)                                                 \
  do {                                                                 \
    const char* ks_ = Ksrc + ((size_t)(cc) << 14) + tid * 16;          \
    const char* vs_ = Vsrc + ((size_t)(cc) << 14) + tid * 16;          \
    char* kd_ = (char*)(&KV[bb][0]) + tid * 16;                        \
    char* vd_ = (char*)(&KV[2 + (bb)][0]) + tid * 16;                  \
    _Pragma("unroll") for (int it = 0; it < 4; ++it) {                 \
      gload_lds16(ks_ + it * 4096, kd_ + it * 4096);                   \
      gload_lds16(vs_ + it * 4096, vd_ + it * 4096);                   \
    }                                                                  \
  } while (0)

__global__ __launch_bounds__(256, 2) void qwen_attn(const unsigned short* __restrict__ Qb,
                                                    const unsigned short* __restrict__ Kswz,
                                                    const unsigned short* __restrict__ Vswz,
                                                    const float* __restrict__ rd,
                                                    unsigned short* __restrict__ AO) {
  __shared__ unsigned short KV[4][8192];  // K0,K1,V0,V1 tiles (16KB each)
  const int bid = blockIdx.x;
  const int kvh = bid & 7;
  const int h = kvh * 2 + ((bid >> 3) & 1);
  const int qt = 31 - (bid >> 4);
  const int q0 = qt * 64;
  const int nch = qt + 1;
  const int tid = threadIdx.x, lane = tid & 63, w = tid >> 6;
  const int l15 = lane & 15, g = lane >> 4;
  const int qw0 = q0 + w * 16;
  const int qlim = qw0 + l15;
  const int swzK = (l15 & 7) << 3;  // ushort-index XOR for K reads
  const int swzV = (l15 & 7) << 2;  // ushort-index XOR for V reads

  // Q frags (B-operand: col=q=l15, k-slot g*8+i <-> d)
  bfrag qF[4];
#pragma unroll
  for (int dc = 0; dc < 4; ++dc)
    qF[dc] = *(const bfrag*)(Qb + ((size_t)h * kS + qw0 + l15) * kHD + dc * 32 + g * 8);
  const float inv = 1.0f / rd[(size_t)h * kS + qw0 + l15];

  const char* Ksrc = (const char*)Kswz + ((size_t)(kvh * 32) << 14);
  const char* Vsrc = (const char*)Vswz + ((size_t)(kvh * 32) << 14);

  f32x4 outa[8] = {};  // out^T: col=q=l15, row(d-within-16-tile)=g*4+r

  STAGE8(0, 0);
#pragma unroll 1
  for (int c = 0; c < nch; ++c) {
    const int b = c & 1;
    if (c + 1 < nch) {
      STAGE8(c + 1, b ^ 1);
      asm volatile("s_waitcnt vmcnt(8)" ::: "memory");  // chunk c landed; c+1 in flight
    } else {
      asm volatile("s_waitcnt vmcnt(0)" ::: "memory");
    }
    __builtin_amdgcn_s_barrier();
    const unsigned short* Kbuf = &KV[b][0];
    const unsigned short* Vbuf = &KV[2 + b][0];
    // QK^T: S^T[key][q] per 16-key tile t
    f32x4 sc[4] = {};
#pragma unroll
    for (int t = 0; t < 4; ++t) {
      const unsigned short* kr = Kbuf + (t * 16 + l15) * 128;
#pragma unroll
      for (int dc = 0; dc < 4; ++dc) {
        bfrag kf = *(const bfrag*)(kr + ((dc * 32 + g * 8) ^ swzK));
        sc[t] = __builtin_amdgcn_mfma_f32_16x16x32_bf16(kf, qF[dc], sc[t], 0, 0, 0);
      }
    }
    // ew ((s*scale + shift)/rd)^8 -> packed PV B-frags (registers only)
    const int kbase = c * 64;
    const bool full = (c < qt);
    union { bfrag f; unsigned u[4]; } pb[2];
#pragma unroll
    for (int t = 0; t < 4; ++t) {
      unsigned short bb[4];
#pragma unroll
      for (int rr = 0; rr < 4; ++rr) {
        float tt = sc[t][rr] * kScale;
        int key = kbase + t * 16 + g * 4 + rr;
        tt += (full || key <= qlim) ? 7.0f : 0.0f;
        float y = tt * inv;
        float y2 = y * y, y4 = y2 * y2;
        bb[rr] = f2b(y4 * y4);
      }
      pb[t >> 1].u[(t & 1) * 2 + 0] = (unsigned)bb[0] | ((unsigned)bb[1] << 16);
      pb[t >> 1].u[(t & 1) * 2 + 1] = (unsigned)bb[2] | ((unsigned)bb[3] << 16);
    }
    // PV: out^T += V^T P^T ; pair pr covers key-16-tiles {2pr,2pr+1}
#pragma unroll
    for (int dt = 0; dt < 8; ++dt) {
      const unsigned short* vr = Vbuf + (dt * 16 + l15) * 64;
#pragma unroll
      for (int pr = 0; pr < 2; ++pr) {
        union { bfrag f; short4v h4[2]; } va;
        va.h4[0] = *(const short4v*)(vr + ((pr * 32 + g * 4) ^ swzV));
        va.h4[1] = *(const short4v*)(vr + ((pr * 32 + 16 + g * 4) ^ swzV));
        outa[dt] = __builtin_amdgcn_mfma_f32_16x16x32_bf16(va.f, pb[pr].f, outa[dt], 0, 0, 0);
      }
    }
    __builtin_amdgcn_s_barrier();  // all waves done with buf b before re-stage
  }
  // AO bf16 [s][h*128+d]
#pragma unroll
  for (int dt = 0; dt < 8; ++dt) {
    short4v o;
    o[0] = (short)f2b(outa[dt][0]); o[1] = (short)f2b(outa[dt][1]);
    o[2] = (short)f2b(outa[dt][2]); o[3] = (short)f2b(outa[dt][3]);
    *(short4v*)(AO + (size_t)(qw0 + l15) * kD + h * 128 + dt * 16 + g * 4) = o;
  }
}

extern "C" void kernel_launch(void* const* d_in, const int* in_sizes, int n_in,
                              void* d_out, int out_size, void* d_ws, size_t ws_size,
                              hipStream_t stream) {
  (void)in_sizes; (void)n_in; (void)out_size; (void)ws_size;
  const float* hidden = (const float*)d_in[0];
  const float* cosb   = (const float*)d_in[1];
  const float* sinb   = (const float*)d_in[2];
  const float* qw     = (const float*)d_in[3];
  const float* kw     = (const float*)d_in[4];
  const float* vw     = (const float*)d_in[5];
  const float* ow     = (const float*)d_in[6];
  const float* qnw    = (const float*)d_in[7];
  const float* knw    = (const float*)d_in[8];
  const float* qden   = (const float*)d_in[9];
  const float* kden   = (const float*)d_in[10];
  const float* rd     = (const float*)d_in[11];
  float* out = (float*)d_out;

  char* ws = (char*)d_ws;
  unsigned short* hsb  = (unsigned short*)(ws + 0 * MB);   //  8 MB
  unsigned short* Wt   = (unsigned short*)(ws + 8 * MB);   // 16 MB
  float*          Cqkv = (float*)(ws + 24 * MB);           // 32 MB
  unsigned short* Qb   = (unsigned short*)(ws + 56 * MB);  //  8 MB
  unsigned short* Kswz = (unsigned short*)(ws + 64 * MB);  //  4 MB
  unsigned short* Vswz = (unsigned short*)(ws + 68 * MB);  //  4 MB
  unsigned short* AO   = (unsigned short*)(ws + 72 * MB);  //  8 MB
  unsigned short* Ot   = (unsigned short*)(ws + 80 * MB);  //  8 MB

  qwen_cast_bf16<<<4096, 256, 0, stream>>>(hidden, hsb, 2048 * 2048 / 4);
  qwen_tw<<<dim3(32, 32), 256, 0, stream>>>(qw, 2048, 2048, Wt, 2048);
  qwen_tw<<<dim3(16, 32), 256, 0, stream>>>(kw, 2048, 1024, Wt + (size_t)2048 * 2048, 2048);
  qwen_tw<<<dim3(16, 32), 256, 0, stream>>>(vw, 2048, 1024, Wt + (size_t)3072 * 2048, 2048);
  qwen_tw<<<dim3(32, 32), 256, 0, stream>>>(ow, 2048, 2048, Ot, 2048);
  qwen_gemm_bt<128><<<dim3(16, 32), 256, 0, stream>>>(hsb, Wt, Cqkv, 2048, 4096, 2048);
  qwen_rope_qk<<<2048, 256, 0, stream>>>(Cqkv, cosb, sinb, qnw, knw, qden, kden, Qb, Kswz);
  qwen_vtr<<<dim3(8, 32, 2), 256, 0, stream>>>(Cqkv, Vswz);
  qwen_attn<<<512, 256, 0, stream>>>(Qb, Kswz, Vswz, rd, AO);
  qwen_gemm_bt<64><<<dim3(32, 16), 256, 0, stream>>>(AO, Ot, out, 2048, 2048, 2048);
}

// Round 9
// 180.700 us; speedup vs baseline: 1.7949x; 1.0212x over previous
//
#include <hip/hip_runtime.h>
#include <cstdint>
#include <cstddef>

// Qwen3AttentionModified: B=1 S=2048 D=2048 H=16 KVH=8 HD=128
// cast hs->bf16; transpose+cast weights; QKV GEMM (2-phase dbuf, counted vmcnt,
// XCD swizzle); RoPE -> Q bf16 + K pre-swizzled tiles; V -> pre-swizzled V^T tiles;
// attention v8 (unchanged, r8-verified): 4-wave block, gload_lds dbuf K/V, vmcnt(8),
// swapped-QK^T zero-shuffle P->PV in regs; O GEMM (BM=128, 2-phase) -> fp32 d_out.

namespace {
constexpr int kS = 2048;
constexpr int kD = 2048;
constexpr int kH = 16;
constexpr int kKVH = 8;
constexpr int kHD = 128;
constexpr float kScale = 0.08838834764831845f;  // 128^-0.5
constexpr size_t MB = 1u << 20;
}  // namespace

using f32x4 = __attribute__((ext_vector_type(4))) float;
using bfrag = __attribute__((ext_vector_type(8))) short;   // 8 x bf16 (4 VGPR)
using float4v = __attribute__((ext_vector_type(4))) float;
using short4v = __attribute__((ext_vector_type(4))) short;

__device__ __forceinline__ unsigned short f2b(float f) {
  union { float f; unsigned u; } x; x.f = f;
  unsigned r = x.u + 0x7FFFu + ((x.u >> 16) & 1u);  // RNE
  return (unsigned short)(r >> 16);
}

__device__ __forceinline__ void gload_lds16(const void* g, void* l) {
  __builtin_amdgcn_global_load_lds(
      (const __attribute__((address_space(1))) unsigned*)g,
      (__attribute__((address_space(3))) unsigned*)l, 16, 0, 0);
}

// ---------------- cast fp32 -> bf16 ----------------
__global__ __launch_bounds__(256) void qwen_cast_bf16(const float* __restrict__ in,
                                                      unsigned short* __restrict__ out,
                                                      int n4) {
  int i = blockIdx.x * 256 + threadIdx.x;
  if (i >= n4) return;
  float4v v = *(const float4v*)(in + (size_t)i * 4);
  short4v o;
  o[0] = (short)f2b(v[0]); o[1] = (short)f2b(v[1]);
  o[2] = (short)f2b(v[2]); o[3] = (short)f2b(v[3]);
  *(short4v*)(out + (size_t)i * 4) = o;
}

// ------------- transpose + cast: fp32 [R][C] -> bf16 [C][ldo] -------------
__global__ __launch_bounds__(256) void qwen_tw(const float* __restrict__ in, int R, int C,
                                               unsigned short* __restrict__ out, int ldo) {
  __shared__ float t[64][65];
  int c0 = blockIdx.x * 64, r0 = blockIdx.y * 64;
  int tr = threadIdx.x >> 6, tc = threadIdx.x & 63;
#pragma unroll
  for (int p = 0; p < 16; ++p) {
    int i = p * 4 + tr;
    t[i][tc] = in[(size_t)(r0 + i) * C + c0 + tc];
  }
  __syncthreads();
#pragma unroll
  for (int p = 0; p < 16; ++p) {
    int i = p * 4 + tr;
    out[(size_t)(c0 + i) * ldo + r0 + tc] = f2b(t[tc][i]);
  }
}

// ------------- GEMM v9: 2-phase dbuf + counted vmcnt (T3-lite) + XCD swizzle -------------
// C[M][N] fp32 = A[M][K] bf16 @ Bt[N][K] bf16
template <int BM>
__global__ __launch_bounds__(256) void qwen_gemm_bt(const unsigned short* __restrict__ A,
                                                    const unsigned short* __restrict__ Bt,
                                                    float* __restrict__ C,
                                                    int M, int N, int K) {
  __shared__ unsigned short As[2][BM * 32];
  __shared__ unsigned short Bs[2][128 * 32];
  constexpr int MR = BM / 32;
  const int nwg = gridDim.x * gridDim.y;
  int lin = blockIdx.y * gridDim.x + blockIdx.x;
  if ((nwg & 7) == 0) { int qq = nwg >> 3; lin = (lin & 7) * qq + (lin >> 3); }
  const int bxx = lin % gridDim.x, byy = lin / gridDim.x;
  const int tid = threadIdx.x, lane = tid & 63, w = tid >> 6;
  const int wr = w >> 1, wc = w & 1;
  const int row0 = bxx * BM, col0 = byy * 128;
  f32x4 acc[MR][4] = {};
  const int koff = (lane >> 4) << 3;
  const int rA = wr * (BM / 2) + (lane & 15);
  const int rB = wc * 64 + (lane & 15);

  auto stage = [&](int kt, int b) {
#pragma unroll
    for (int c = 0; c < BM / 64; ++c) {
      int off = (c * 256 + tid) * 16;
      int e = off >> 1;
      int r = e >> 5, cc = e & 31;
      gload_lds16(A + (size_t)(row0 + r) * K + kt + cc, (char*)(&As[b][0]) + off);
    }
#pragma unroll
    for (int c = 0; c < 2; ++c) {
      int off = (c * 256 + tid) * 16;
      int e = off >> 1;
      int r = e >> 5, cc = e & 31;
      gload_lds16(Bt + (size_t)(col0 + r) * K + kt + cc, (char*)(&Bs[b][0]) + off);
    }
  };

  const int nk = K >> 5;
  stage(0, 0);
  asm volatile("s_waitcnt vmcnt(0)" ::: "memory");
  __builtin_amdgcn_s_barrier();
  int buf = 0;
#pragma unroll 1
  for (int t = 0; t < nk; ++t) {
    if (t + 1 < nk) stage((t + 1) << 5, buf ^ 1);  // next tile in flight across compute
    bfrag aF[MR], bF[4];
#pragma unroll
    for (int m = 0; m < MR; ++m)
      aF[m] = *(const bfrag*)(&As[buf][0] + (rA + m * 16) * 32 + koff);
#pragma unroll
    for (int n = 0; n < 4; ++n)
      bF[n] = *(const bfrag*)(&Bs[buf][0] + (rB + n * 16) * 32 + koff);
#pragma unroll
    for (int m = 0; m < MR; ++m)
#pragma unroll
      for (int n = 0; n < 4; ++n)
        acc[m][n] = __builtin_amdgcn_mfma_f32_16x16x32_bf16(aF[m], bF[n], acc[m][n], 0, 0, 0);
    asm volatile("s_waitcnt vmcnt(0)" ::: "memory");  // next tile landed (overlapped)
    __builtin_amdgcn_s_barrier();
    buf ^= 1;
  }
  const int cr = (lane >> 4) << 2;
  const int cc2 = lane & 15;
#pragma unroll
  for (int m = 0; m < MR; ++m)
#pragma unroll
    for (int n = 0; n < 4; ++n) {
      int r = row0 + wr * (BM / 2) + m * 16 + cr;
      int c = col0 + wc * 64 + n * 16 + cc2;
#pragma unroll
      for (int j = 0; j < 4; ++j) C[(size_t)(r + j) * N + c] = acc[m][n][j];
    }
}

// ------------- RoPE: Q -> bf16 [h][s][d]; K -> pre-swizzled 64-key tiles -------------
// Kswz tile (kvh, kt): 64 rows(key) x 128 us(d); elem idx = d ^ ((key&7)<<3)
__global__ __launch_bounds__(256) void qwen_rope_qk(const float* __restrict__ Cqkv,
                                                    const float* __restrict__ cosb,
                                                    const float* __restrict__ sinb,
                                                    const float* __restrict__ qnw,
                                                    const float* __restrict__ knw,
                                                    const float* __restrict__ qden,
                                                    const float* __restrict__ kden,
                                                    unsigned short* __restrict__ Qb,
                                                    unsigned short* __restrict__ Kswz) {
  int s = blockIdx.x;
  int t = threadIdx.x;
  const float* row = Cqkv + (size_t)s * 4096;
  const float* cs = cosb + (size_t)s * kHD;
  const float* sn = sinb + (size_t)s * kHD;
#pragma unroll
  for (int rep = 0; rep < 8; ++rep) {
    int idx = rep * 256 + t;
    int h = idx >> 7, d = idx & 127;
    float dn = qden[s * kH + h];
    float v = row[idx] * dn * qnw[d];
    float pv = row[(h << 7) + (d ^ 64)] * dn * qnw[d ^ 64];
    float rot = (d < 64) ? -pv : pv;
    Qb[((size_t)h * kS + s) * kHD + d] = f2b(v * cs[d] + rot * sn[d]);
  }
  const int kt = s >> 6, key = s & 63;
#pragma unroll
  for (int rep = 0; rep < 4; ++rep) {
    int idx = rep * 256 + t;
    int h = idx >> 7, d = idx & 127;  // h = kvh
    float dn = kden[s * kKVH + h];
    float v = row[2048 + idx] * dn * knw[d];
    float pv = row[2048 + (h << 7) + (d ^ 64)] * dn * knw[d ^ 64];
    float rot = (d < 64) ? -pv : pv;
    size_t rowi = ((size_t)(h * 32 + kt) * 64 + key) * 128;
    Kswz[rowi + (d ^ ((key & 7) << 3))] = f2b(v * cs[d] + rot * sn[d]);
  }
}

// ------------- V -> pre-swizzled V^T tiles: (kvh, kt): 128 rows(d) x 64 us(key) -------------
// elem idx = key ^ ((d&7)<<2)
__global__ __launch_bounds__(256) void qwen_vtr(const float* __restrict__ Cqkv,
                                                unsigned short* __restrict__ Vswz) {
  __shared__ float t[64][65];
  int kvh = blockIdx.x, st = blockIdx.y, dt = blockIdx.z;
  int s0 = st * 64, d0 = dt * 64;
  int tr = threadIdx.x >> 6, tc = threadIdx.x & 63;
#pragma unroll
  for (int p = 0; p < 16; ++p) {
    int i = p * 4 + tr;
    t[i][tc] = Cqkv[(size_t)(s0 + i) * 4096 + 3072 + (kvh << 7) + d0 + tc];
  }
  __syncthreads();
#pragma unroll
  for (int p = 0; p < 16; ++p) {
    int i = p * 4 + tr;
    int d = d0 + i;
    size_t rowi = ((size_t)(kvh * 32 + st) * 128 + d) * 64;
    Vswz[rowi + (tc ^ ((d & 7) << 2))] = f2b(t[tc][i]);
  }
}

// ------------- attention v8 (r8-verified): counted-vmcnt pipeline -------------
// 512 blocks x 256 thr. kvh=bid&7 (XCD-bound); h=kvh*2+((bid>>3)&1); qt=31-(bid>>4)
// (64-row q tile, heavy first). Wave w owns q rows qw0=qt*64+w*16 (+l15).
// Per 64-key chunk c: STAGE(c+1) -> vmcnt(8) -> barrier -> QK(16 mfma from swizzled
// LDS K) -> ew+pack in regs -> PV(16 mfma, V^T b64 pairs from LDS) -> barrier.
#define STAGE8(cc, bb)                                                 \
  do {                                                                 \
    const char* ks_ = Ksrc + ((size_t)(cc) << 14) + tid * 16;          \
    const char* vs_ = Vsrc + ((size_t)(cc) << 14) + tid * 16;          \
    char* kd_ = (char*)(&KV[bb][0]) + tid * 16;                        \
    char* vd_ = (char*)(&KV[2 + (bb)][0]) + tid * 16;                  \
    _Pragma("unroll") for (int it = 0; it < 4; ++it) {                 \
      gload_lds16(ks_ + it * 4096, kd_ + it * 4096);                   \
      gload_lds16(vs_ + it * 4096, vd_ + it * 4096);                   \
    }                                                                  \
  } while (0)

__global__ __launch_bounds__(256, 2) void qwen_attn(const unsigned short* __restrict__ Qb,
                                                    const unsigned short* __restrict__ Kswz,
                                                    const unsigned short* __restrict__ Vswz,
                                                    const float* __restrict__ rd,
                                                    unsigned short* __restrict__ AO) {
  __shared__ unsigned short KV[4][8192];  // K0,K1,V0,V1 tiles (16KB each)
  const int bid = blockIdx.x;
  const int kvh = bid & 7;
  const int h = kvh * 2 + ((bid >> 3) & 1);
  const int qt = 31 - (bid >> 4);
  const int q0 = qt * 64;
  const int nch = qt + 1;
  const int tid = threadIdx.x, lane = tid & 63, w = tid >> 6;
  const int l15 = lane & 15, g = lane >> 4;
  const int qw0 = q0 + w * 16;
  const int qlim = qw0 + l15;
  const int swzK = (l15 & 7) << 3;  // ushort-index XOR for K reads
  const int swzV = (l15 & 7) << 2;  // ushort-index XOR for V reads

  // Q frags (B-operand: col=q=l15, k-slot g*8+i <-> d)
  bfrag qF[4];
#pragma unroll
  for (int dc = 0; dc < 4; ++dc)
    qF[dc] = *(const bfrag*)(Qb + ((size_t)h * kS + qw0 + l15) * kHD + dc * 32 + g * 8);
  const float inv = 1.0f / rd[(size_t)h * kS + qw0 + l15];

  const char* Ksrc = (const char*)Kswz + ((size_t)(kvh * 32) << 14);
  const char* Vsrc = (const char*)Vswz + ((size_t)(kvh * 32) << 14);

  f32x4 outa[8] = {};  // out^T: col=q=l15, row(d-within-16-tile)=g*4+r

  STAGE8(0, 0);
#pragma unroll 1
  for (int c = 0; c < nch; ++c) {
    const int b = c & 1;
    if (c + 1 < nch) {
      STAGE8(c + 1, b ^ 1);
      asm volatile("s_waitcnt vmcnt(8)" ::: "memory");  // chunk c landed; c+1 in flight
    } else {
      asm volatile("s_waitcnt vmcnt(0)" ::: "memory");
    }
    __builtin_amdgcn_s_barrier();
    const unsigned short* Kbuf = &KV[b][0];
    const unsigned short* Vbuf = &KV[2 + b][0];
    // QK^T: S^T[key][q] per 16-key tile t
    f32x4 sc[4] = {};
#pragma unroll
    for (int t = 0; t < 4; ++t) {
      const unsigned short* kr = Kbuf + (t * 16 + l15) * 128;
#pragma unroll
      for (int dc = 0; dc < 4; ++dc) {
        bfrag kf = *(const bfrag*)(kr + ((dc * 32 + g * 8) ^ swzK));
        sc[t] = __builtin_amdgcn_mfma_f32_16x16x32_bf16(kf, qF[dc], sc[t], 0, 0, 0);
      }
    }
    // ew ((s*scale + shift)/rd)^8 -> packed PV B-frags (registers only)
    const int kbase = c * 64;
    const bool full = (c < qt);
    union { bfrag f; unsigned u[4]; } pb[2];
#pragma unroll
    for (int t = 0; t < 4; ++t) {
      unsigned short bb[4];
#pragma unroll
      for (int rr = 0; rr < 4; ++rr) {
        float tt = sc[t][rr] * kScale;
        int key = kbase + t * 16 + g * 4 + rr;
        tt += (full || key <= qlim) ? 7.0f : 0.0f;
        float y = tt * inv;
        float y2 = y * y, y4 = y2 * y2;
        bb[rr] = f2b(y4 * y4);
      }
      pb[t >> 1].u[(t & 1) * 2 + 0] = (unsigned)bb[0] | ((unsigned)bb[1] << 16);
      pb[t >> 1].u[(t & 1) * 2 + 1] = (unsigned)bb[2] | ((unsigned)bb[3] << 16);
    }
    // PV: out^T += V^T P^T ; pair pr covers key-16-tiles {2pr,2pr+1}
#pragma unroll
    for (int dt = 0; dt < 8; ++dt) {
      const unsigned short* vr = Vbuf + (dt * 16 + l15) * 64;
#pragma unroll
      for (int pr = 0; pr < 2; ++pr) {
        union { bfrag f; short4v h4[2]; } va;
        va.h4[0] = *(const short4v*)(vr + ((pr * 32 + g * 4) ^ swzV));
        va.h4[1] = *(const short4v*)(vr + ((pr * 32 + 16 + g * 4) ^ swzV));
        outa[dt] = __builtin_amdgcn_mfma_f32_16x16x32_bf16(va.f, pb[pr].f, outa[dt], 0, 0, 0);
      }
    }
    __builtin_amdgcn_s_barrier();  // all waves done with buf b before re-stage
  }
  // AO bf16 [s][h*128+d]
#pragma unroll
  for (int dt = 0; dt < 8; ++dt) {
    short4v o;
    o[0] = (short)f2b(outa[dt][0]); o[1] = (short)f2b(outa[dt][1]);
    o[2] = (short)f2b(outa[dt][2]); o[3] = (short)f2b(outa[dt][3]);
    *(short4v*)(AO + (size_t)(qw0 + l15) * kD + h * 128 + dt * 16 + g * 4) = o;
  }
}

extern "C" void kernel_launch(void* const* d_in, const int* in_sizes, int n_in,
                              void* d_out, int out_size, void* d_ws, size_t ws_size,
                              hipStream_t stream) {
  (void)in_sizes; (void)n_in; (void)out_size; (void)ws_size;
  const float* hidden = (const float*)d_in[0];
  const float* cosb   = (const float*)d_in[1];
  const float* sinb   = (const float*)d_in[2];
  const float* qw     = (const float*)d_in[3];
  const float* kw     = (const float*)d_in[4];
  const float* vw     = (const float*)d_in[5];
  const float* ow     = (const float*)d_in[6];
  const float* qnw    = (const float*)d_in[7];
  const float* knw    = (const float*)d_in[8];
  const float* qden   = (const float*)d_in[9];
  const float* kden   = (const float*)d_in[10];
  const float* rd     = (const float*)d_in[11];
  float* out = (float*)d_out;

  char* ws = (char*)d_ws;
  unsigned short* hsb  = (unsigned short*)(ws + 0 * MB);   //  8 MB
  unsigned short* Wt   = (unsigned short*)(ws + 8 * MB);   // 16 MB
  float*          Cqkv = (float*)(ws + 24 * MB);           // 32 MB
  unsigned short* Qb   = (unsigned short*)(ws + 56 * MB);  //  8 MB
  unsigned short* Kswz = (unsigned short*)(ws + 64 * MB);  //  4 MB
  unsigned short* Vswz = (unsigned short*)(ws + 68 * MB);  //  4 MB
  unsigned short* AO   = (unsigned short*)(ws + 72 * MB);  //  8 MB
  unsigned short* Ot   = (unsigned short*)(ws + 80 * MB);  //  8 MB

  qwen_cast_bf16<<<4096, 256, 0, stream>>>(hidden, hsb, 2048 * 2048 / 4);
  qwen_tw<<<dim3(32, 32), 256, 0, stream>>>(qw, 2048, 2048, Wt, 2048);
  qwen_tw<<<dim3(16, 32), 256, 0, stream>>>(kw, 2048, 1024, Wt + (size_t)2048 * 2048, 2048);
  qwen_tw<<<dim3(16, 32), 256, 0, stream>>>(vw, 2048, 1024, Wt + (size_t)3072 * 2048, 2048);
  qwen_tw<<<dim3(32, 32), 256, 0, stream>>>(ow, 2048, 2048, Ot, 2048);
  qwen_gemm_bt<128><<<dim3(16, 32), 256, 0, stream>>>(hsb, Wt, Cqkv, 2048, 4096, 2048);
  qwen_rope_qk<<<2048, 256, 0, stream>>>(Cqkv, cosb, sinb, qnw, knw, qden, kden, Qb, Kswz);
  qwen_vtr<<<dim3(8, 32, 2), 256, 0, stream>>>(Cqkv, Vswz);
  qwen_attn<<<512, 256, 0, stream>>>(Qb, Kswz, Vswz, rd, AO);
  qwen_gemm_bt<128><<<dim3(16, 16), 256, 0, stream>>>(AO, Ot, out, 2048, 2048, 2048);
}